// Round 6
// baseline (445.664 us; speedup 1.0000x reference)
//
#include <hip/hip_runtime.h>
#include <hip/hip_bf16.h>

#define N_  32
#define ND_ 16
#define ED_ 8
#define GD_ 8
#define HN_ 128
#define HE_ 128
#define HG_ 128
#define HC_ 64

typedef __attribute__((ext_vector_type(8))) short short8_t;
typedef __attribute__((ext_vector_type(4))) float f32x4;

#define MFMA16(a, b, c) __builtin_amdgcn_mfma_f32_16x16x32_bf16((a), (b), (c), 0, 0, 0)

__device__ __forceinline__ unsigned short f2bf(float f) {
    unsigned int u = __float_as_uint(f);
    unsigned int r = u + 0x7FFFu + ((u >> 16) & 1u);
    return (unsigned short)(r >> 16);
}
__device__ __forceinline__ float bf2f(unsigned short h) {
    return __uint_as_float(((unsigned int)h) << 16);
}

// ---- workspace layout (ushort elements) ----
#define WNS_HI 0
#define WNS_LO 4096
#define WES_HI 8192
#define WES_LO (8192 + 36864)
#define WS_USHORTS (8192 + 2 * 36864)
#define WS_BYTES (WS_USHORTS * 2)

// Prologue: convert + swizzle weights into B-fragment-major bf16 hi/lo.
// lane l holds B[k = 32*s + 8*(l>>4)+i][col = 16*n + (l&15)]
__global__ void prep_weights(const float* __restrict__ Wn,
                             const float* __restrict__ We,
                             unsigned short* __restrict__ wsp) {
    int gid = blockIdx.x * 256 + threadIdx.x;
    if (gid >= 512 + 4608) return;
    float vals[8];
    unsigned short* dh;
    unsigned short* dl;
    if (gid < 512) {
        int l = gid & 63, n = (gid >> 6) & 7;
        int c = 16 * n + (l & 15);
#pragma unroll
        for (int i = 0; i < 8; ++i) {
            int k = 8 * (l >> 4) + i;
            vals[i] = Wn[k * HN_ + c];
        }
        dh = wsp + WNS_HI + gid * 8;
        dl = wsp + WNS_LO + gid * 8;
    } else {
        int g2 = gid - 512;
        int l = g2 & 63, n = (g2 >> 6) & 7, s = g2 >> 9;   // s in 0..8
        int c = 16 * n + (l & 15);
#pragma unroll
        for (int i = 0; i < 8; ++i) {
            int kl = 8 * (l >> 4) + i;
            int ks;
            if (s == 0)      ks = (kl < 8) ? kl : -1;          // ef rows 0..7
            else if (s <= 4) ks = 8 + (s - 1) * 32 + kl;       // W1: h_node[e]
            else             ks = 136 + (s - 5) * 32 + kl;     // W2: h_node[e+1]
            vals[i] = (ks >= 0) ? We[ks * HE_ + c] : 0.0f;
        }
        dh = wsp + WES_HI + g2 * 8;
        dl = wsp + WES_LO + g2 * 8;
    }
    unsigned short h[8], lo[8];
#pragma unroll
    for (int i = 0; i < 8; ++i) {
        h[i] = f2bf(vals[i]);
        lo[i] = f2bf(vals[i] - bf2f(h[i]));
    }
    *(short8_t*)dh = *(short8_t*)h;
    *(short8_t*)dl = *(short8_t*)lo;
}

#define HNS 136   // 272 B rows: 16B-aligned
#define NIS 40    // 80 B rows: 16B-aligned (80 = 5*16)
#define HES 132   // f32 rows 528 B: 16B-aligned

// Persistent weight-stationary kernel: grid <=512 (2 blocks/CU), each block
// loops over pairs of graphs. Edge W1/W2 B-fragments live in VGPRs (128);
// node/e0 fragments reloaded from L2 per iteration (LICM defeated via asm).
__global__ __launch_bounds__(256, 2) void gnn_persist(
    const float* __restrict__ gf, const float* __restrict__ nf,
    const float* __restrict__ ef, const void* __restrict__ nmask_raw,
    const float* __restrict__ Wn, const float* __restrict__ bn,
    const float* __restrict__ We, const float* __restrict__ be,
    const float* __restrict__ Ws, const float* __restrict__ bs,
    const float* __restrict__ Wg, const float* __restrict__ bg,
    const float* __restrict__ Wc1, const float* __restrict__ bc1,
    const float* __restrict__ Wc2, const float* __restrict__ bc2,
    const unsigned short* __restrict__ wsp,
    float* __restrict__ out, int Btot, int npairs)
{
    const int t = threadIdx.x;
    const int w = t >> 6, l = t & 63;
    const int lrow = l & 15;
    const int lk8 = (l >> 4) * 8;
    const int g4 = (l >> 4) * 4;
    const int c0 = 32 * w + lrow, c1 = c0 + 16;

    __shared__ __align__(16) unsigned short s_hn_h[2][N_ + 1][HNS];
    __shared__ __align__(16) unsigned short s_hn_l[2][N_ + 1][HNS];
    __shared__ __align__(16) unsigned char u_mem[33792];   // union {nin,efp} / s_he
    __shared__ __align__(16) float s_bias1[2][HN_];
    __shared__ __align__(16) float s_bias2[2][HE_];
    __shared__ float s_g[2][GD_];
    __shared__ int   s_mi[2][N_];
    __shared__ float s_emask[2][N_];
    __shared__ float s_sc[2][N_];
    __shared__ float s_w[2][N_];
    __shared__ __align__(16) float s_tmp[512];
    __shared__ __align__(16) float s_aggf[2][HE_];
    __shared__ __align__(16) float s_hg[2][HG_];
    __shared__ __align__(16) float s_hc[2][HC_];
    __shared__ __align__(16) float s_Ws[128];
    __shared__ float s_Wc2[64], s_bn[128], s_be[128], s_bg[128], s_bc1[64];
    __shared__ float s_bs2[2];

    typedef unsigned short ninrow_t[NIS];
    ninrow_t* s_nin_h = (ninrow_t*)(u_mem);            // [64][40]
    ninrow_t* s_nin_l = (ninrow_t*)(u_mem + 5120);
    ninrow_t* s_efp_h = (ninrow_t*)(u_mem + 10240);
    ninrow_t* s_efp_l = (ninrow_t*)(u_mem + 15360);
    typedef float herow_t[HES];
    herow_t* s_he = (herow_t*)u_mem;                   // [64][132]

    // ---- mask dtype detection (u8 vs i32), deterministic ----
    const unsigned char* mb = (const unsigned char*)nmask_raw;
    int cnt = __syncthreads_count(mb[t] != 0);
    const bool is_u8 = (cnt > 96);

    // ---- persistent B fragments: edge W1/W2 only (32 x short8 = 128 VGPRs) ----
    short8_t e1h[4][2], e1l[4][2], e2h[4][2], e2l[4][2];
#pragma unroll
    for (int nt = 0; nt < 2; ++nt) {
        int n = 2 * w + nt;
#pragma unroll
        for (int s = 0; s < 4; ++s) {
            e1h[s][nt] = *(const short8_t*)(wsp + WES_HI + ((s + 1) * 8 + n) * 512 + l * 8);
            e1l[s][nt] = *(const short8_t*)(wsp + WES_LO + ((s + 1) * 8 + n) * 512 + l * 8);
            e2h[s][nt] = *(const short8_t*)(wsp + WES_HI + ((s + 5) * 8 + n) * 512 + l * 8);
            e2l[s][nt] = *(const short8_t*)(wsp + WES_LO + ((s + 5) * 8 + n) * 512 + l * 8);
        }
    }

    // ---- prologue: hn pad row 32 = 0 (never overwritten) + small weights ----
    for (int idx = t; idx < 2 * HNS; idx += 256) {
        int g = (idx >= HNS), c = idx - g * HNS;
        s_hn_h[g][N_][c] = 0; s_hn_l[g][N_][c] = 0;
    }
    if (t < 128) {
        s_Ws[t] = Ws[t]; s_bn[t] = bn[t]; s_be[t] = be[t]; s_bg[t] = bg[t];
    } else {
        int j = t - 128;
        if (j < 64) { s_Wc2[j] = Wc2[j]; s_bc1[j] = bc1[j]; }
        if (j == 64) { s_bs2[0] = bs[0]; s_bs2[1] = bc2[0]; }
    }

    // ---- initial prefetch for pair p0 ----
    int p0 = blockIdx.x;
    float4 pfN;
    float pfE0, pfE1, pfG;
    unsigned int pfM;
    {
        int pp = (p0 < npairs) ? p0 : 0;
        int gid0 = min(2 * pp, Btot - 1), gid1 = min(2 * pp + 1, Btot - 1);
        int gA = (4 * t) >> 9, remA = (4 * t) & 511;
        pfN = *(const float4*)(nf + (gA ? gid1 : gid0) * 512 + remA);
        pfE0 = (t < 248) ? ef[gid0 * 248 + t] : 0.0f;
        pfE1 = (t < 248) ? ef[gid1 * 248 + t] : 0.0f;
        pfG = (t < 16) ? gf[((t >> 3) ? gid1 : gid0) * GD_ + (t & 7)] : 0.0f;
        if (is_u8) {
            pfM = (t < 16) ? ((const unsigned int*)mb)[((t >> 3) ? gid1 : gid0) * 8 + (t & 7)] : 0u;
        } else {
            pfM = (t < 64) ? ((const unsigned int*)nmask_raw)[((t >> 5) ? gid1 : gid0) * 32 + (t & 31)] : 0u;
        }
    }
    __syncthreads();

    for (int p = p0; p < npairs; p += gridDim.x) {
        // ---- Phase A: re-zero union padding (s_he overwrote it last iter),
        //      then decode prefetch regs -> LDS ----
        {
            float4 zf = {0.0f, 0.0f, 0.0f, 0.0f};
#pragma unroll
            for (int ii = 0; ii < 2; ++ii) {
                int c = t + ii * 256;              // 0..511
                int a = c >> 8, rem = c & 255;
                int r = rem >> 2, q = rem & 3;
                unsigned short* base = a ? &s_efp_l[r][8] : &s_efp_h[r][8];
                *(float4*)(base + q * 8) = zf;
            }
            if (t < 16) {                          // node0/node32 edge_backward = 0
                int g = t >> 3, k = t & 7;
                s_nin_h[g * 32][16 + k] = 0; s_nin_l[g * 32][16 + k] = 0;
            }
        }
        {
            int gA = (4 * t) >> 9, remA = (4 * t) & 511;
            int rA = gA * 32 + (remA >> 4), kA = remA & 15;
            float vv[4] = {pfN.x, pfN.y, pfN.z, pfN.w};
#pragma unroll
            for (int i = 0; i < 4; ++i) {
                unsigned short h = f2bf(vv[i]);
                s_nin_h[rA][kA + i] = h;
                s_nin_l[rA][kA + i] = f2bf(vv[i] - bf2f(h));
            }
            if (t < 248) {
                int e = t >> 3, k = t & 7;
                unsigned short h0 = f2bf(pfE0);
                s_efp_h[e][k] = h0;
                s_efp_l[e][k] = f2bf(pfE0 - bf2f(h0));
                unsigned short h1 = f2bf(pfE1);
                s_efp_h[32 + e][k] = h1;
                s_efp_l[32 + e][k] = f2bf(pfE1 - bf2f(h1));
            } else if (t < 252) {
                int g = (t - 248) >> 1, k4 = ((t - 248) & 1) * 4;
#pragma unroll
                for (int i = 0; i < 4; ++i) {
                    s_efp_h[g * 32 + 31][k4 + i] = 0;
                    s_efp_l[g * 32 + 31][k4 + i] = 0;
                }
            }
            if (t < 16) s_g[t >> 3][t & 7] = pfG;
            if (is_u8) {
                if (t < 16) {
                    int g = t >> 3, base = (t & 7) * 4;
#pragma unroll
                    for (int i = 0; i < 4; ++i)
                        s_mi[g][base + i] = (int)((pfM >> (8 * i)) & 0xffu);
                }
            } else {
                if (t < 64) s_mi[t >> 5][t & 31] = (int)pfM;
            }
        }
        // issue prefetch for next pair
        {
            int pn = p + gridDim.x;
            if (pn < npairs) {
                int ngid0 = min(2 * pn, Btot - 1), ngid1 = min(2 * pn + 1, Btot - 1);
                int gA = (4 * t) >> 9, remA = (4 * t) & 511;
                pfN = *(const float4*)(nf + (gA ? ngid1 : ngid0) * 512 + remA);
                if (t < 248) {
                    pfE0 = ef[ngid0 * 248 + t];
                    pfE1 = ef[ngid1 * 248 + t];
                }
                if (t < 16) pfG = gf[((t >> 3) ? ngid1 : ngid0) * GD_ + (t & 7)];
                if (is_u8) {
                    if (t < 16) pfM = ((const unsigned int*)mb)[((t >> 3) ? ngid1 : ngid0) * 8 + (t & 7)];
                } else {
                    if (t < 64) pfM = ((const unsigned int*)nmask_raw)[((t >> 5) ? ngid1 : ngid0) * 32 + (t & 31)];
                }
            }
        }
        __syncthreads();

        // ---- Phase B: emask + combined biases + nin tail from efp ----
        if (t < 64) {
            int g = t >> 5, n = t & 31;
            s_emask[g][n] = (n < 31 && s_mi[g][n] != 0 && s_mi[g][n + 1] != 0) ? 1.0f : 0.0f;
        }
        {
            int mat = t >> 7, j = t & 127;
            const float* Wt = mat ? (We + (ED_ + 2 * HN_) * HE_) : (Wn + (ND_ + 2 * ED_) * HN_);
            float base = mat ? s_be[j] : s_bn[j];
            float a0 = base, a1 = base;
#pragma unroll
            for (int k = 0; k < GD_; ++k) {
                float wv = Wt[k * 128 + j];
                a0 += s_g[0][k] * wv;
                a1 += s_g[1][k] * wv;
            }
            if (mat) { s_bias2[0][j] = a0; s_bias2[1][j] = a1; }
            else     { s_bias1[0][j] = a0; s_bias1[1][j] = a1; }
        }
#pragma unroll
        for (int ii = 0; ii < 2; ++ii) {
            int idx = t + ii * 256;
            int g = idx >> 8, rem = idx & 255, e = rem >> 3, k = rem & 7;
            int r = g * 32 + e;
            bool m = (e < 31) && s_mi[g][e] != 0 && s_mi[g][e + 1] != 0;
            unsigned short h = m ? s_efp_h[r][k] : (unsigned short)0;
            unsigned short lo2 = m ? s_efp_l[r][k] : (unsigned short)0;
            if (e < 31) { s_nin_h[r + 1][16 + k] = h; s_nin_l[r + 1][16 + k] = lo2; }
            s_nin_h[r][24 + k] = h;
            s_nin_l[r][24 + k] = lo2;
        }
        __syncthreads();

        // ---- Node MLP (MFMA, K=32): B fragments loaded per-iter from L2 ----
        {
            // LICM-defeating opaque pointer: keep these 4 loads inside the loop
            const unsigned short* pn = wsp + (2 * w) * 512 + l * 8;
            asm volatile("" : "+v"(pn));
            short8_t nBh0 = *(const short8_t*)(pn + WNS_HI);
            short8_t nBl0 = *(const short8_t*)(pn + WNS_LO);
            short8_t nBh1 = *(const short8_t*)(pn + WNS_HI + 512);
            short8_t nBl1 = *(const short8_t*)(pn + WNS_LO + 512);

            f32x4 acc[4][2];
#pragma unroll
            for (int mt = 0; mt < 4; ++mt) {
                int g = mt >> 1;
                float b0 = s_bias1[g][c0], b1 = s_bias1[g][c1];
                acc[mt][0] = (f32x4){b0, b0, b0, b0};
                acc[mt][1] = (f32x4){b1, b1, b1, b1};
            }
#pragma unroll
            for (int mt = 0; mt < 4; ++mt) {
                int r = mt * 16 + lrow;
                short8_t Ah = *(const short8_t*)&s_nin_h[r][lk8];
                short8_t Al = *(const short8_t*)&s_nin_l[r][lk8];
                acc[mt][0] = MFMA16(Al, nBh0, acc[mt][0]);
                acc[mt][0] = MFMA16(Ah, nBl0, acc[mt][0]);
                acc[mt][0] = MFMA16(Ah, nBh0, acc[mt][0]);
                acc[mt][1] = MFMA16(Al, nBh1, acc[mt][1]);
                acc[mt][1] = MFMA16(Ah, nBl1, acc[mt][1]);
                acc[mt][1] = MFMA16(Ah, nBh1, acc[mt][1]);
            }
#pragma unroll
            for (int mt = 0; mt < 4; ++mt) {
                int g = mt >> 1, rb = (mt & 1) * 16 + g4;
#pragma unroll
                for (int nt = 0; nt < 2; ++nt) {
                    int col = nt ? c1 : c0;
#pragma unroll
                    for (int r = 0; r < 4; ++r) {
                        float v = fmaxf(acc[mt][nt][r], 0.0f);
                        unsigned short h = f2bf(v);
                        s_hn_h[g][rb + r][col] = h;
                        s_hn_l[g][rb + r][col] = f2bf(v - bf2f(h));
                    }
                }
            }
        }
        __syncthreads();

        // ---- Edge MLP: acc = bias2 + ef@W0 + hn[e]@W1 + hn[e+1]@W2 ----
        float hev[4][2][4];
        {
            f32x4 acc[4][2];
#pragma unroll
            for (int mt = 0; mt < 4; ++mt) {
                int g = mt >> 1;
                float b0 = s_bias2[g][c0], b1 = s_bias2[g][c1];
                acc[mt][0] = (f32x4){b0, b0, b0, b0};
                acc[mt][1] = (f32x4){b1, b1, b1, b1};
            }
            // step0: raw edge features; B fragments loaded per-iter from L2
            {
                const unsigned short* pe = wsp + WES_HI + (2 * w) * 512 + l * 8;
                asm volatile("" : "+v"(pe));
                short8_t E0h0 = *(const short8_t*)(pe);
                short8_t E0l0 = *(const short8_t*)(pe + 36864);
                short8_t E0h1 = *(const short8_t*)(pe + 512);
                short8_t E0l1 = *(const short8_t*)(pe + 36864 + 512);
#pragma unroll
                for (int mt = 0; mt < 4; ++mt) {
                    int r = mt * 16 + lrow;
                    short8_t Ah = *(const short8_t*)&s_efp_h[r][lk8];
                    short8_t Al = *(const short8_t*)&s_efp_l[r][lk8];
                    acc[mt][0] = MFMA16(Al, E0h0, acc[mt][0]);
                    acc[mt][0] = MFMA16(Ah, E0l0, acc[mt][0]);
                    acc[mt][0] = MFMA16(Ah, E0h0, acc[mt][0]);
                    acc[mt][1] = MFMA16(Al, E0h1, acc[mt][1]);
                    acc[mt][1] = MFMA16(Ah, E0l1, acc[mt][1]);
                    acc[mt][1] = MFMA16(Ah, E0h1, acc[mt][1]);
                }
            }
            // steps 1..4: A1 = hn[e], A2 = hn[e+1] (row-shift, shared acc)
#pragma unroll
            for (int s = 0; s < 4; ++s) {
                int kb = s * 32 + lk8;
#pragma unroll
                for (int mt = 0; mt < 4; ++mt) {
                    int g = mt >> 1, lr = (mt & 1) * 16 + lrow;
                    short8_t A1h = *(const short8_t*)&s_hn_h[g][lr][kb];
                    short8_t A1l = *(const short8_t*)&s_hn_l[g][lr][kb];
                    short8_t A2h = *(const short8_t*)&s_hn_h[g][lr + 1][kb];
                    short8_t A2l = *(const short8_t*)&s_hn_l[g][lr + 1][kb];
                    acc[mt][0] = MFMA16(A1l, e1h[s][0], acc[mt][0]);
                    acc[mt][0] = MFMA16(A1h, e1l[s][0], acc[mt][0]);
                    acc[mt][0] = MFMA16(A1h, e1h[s][0], acc[mt][0]);
                    acc[mt][1] = MFMA16(A1l, e1h[s][1], acc[mt][1]);
                    acc[mt][1] = MFMA16(A1h, e1l[s][1], acc[mt][1]);
                    acc[mt][1] = MFMA16(A1h, e1h[s][1], acc[mt][1]);
                    acc[mt][0] = MFMA16(A2l, e2h[s][0], acc[mt][0]);
                    acc[mt][0] = MFMA16(A2h, e2l[s][0], acc[mt][0]);
                    acc[mt][0] = MFMA16(A2h, e2h[s][0], acc[mt][0]);
                    acc[mt][1] = MFMA16(A2l, e2h[s][1], acc[mt][1]);
                    acc[mt][1] = MFMA16(A2h, e2l[s][1], acc[mt][1]);
                    acc[mt][1] = MFMA16(A2h, e2h[s][1], acc[mt][1]);
                }
            }
#pragma unroll
            for (int mt = 0; mt < 4; ++mt)
#pragma unroll
                for (int nt = 0; nt < 2; ++nt)
#pragma unroll
                    for (int r = 0; r < 4; ++r)
                        hev[mt][nt][r] = fmaxf(acc[mt][nt][r], 0.0f);
        }
        __syncthreads();   // all efp/nin reads done -> safe to overlay s_he
#pragma unroll
        for (int mt = 0; mt < 4; ++mt) {
            int rb = mt * 16 + g4;
#pragma unroll
            for (int nt = 0; nt < 2; ++nt) {
                int col = nt ? c1 : c0;
#pragma unroll
                for (int r = 0; r < 4; ++r)
                    s_he[rb + r][col] = hev[mt][nt][r];
            }
        }
        __syncthreads();

        // ---- P3: scores ----
        {
            int c = t & 3, eg = t >> 2;
            int g = eg >> 5, e = eg & 31;
            const float* he = &s_he[g * 32 + e][0];
            float pq = 0.0f;
#pragma unroll
            for (int j0 = 0; j0 < 32; j0 += 4) {
                float4 h = *(const float4*)&he[c * 32 + j0];
                float4 wv = *(const float4*)&s_Ws[c * 32 + j0];
                pq += h.x * wv.x + h.y * wv.y + h.z * wv.z + h.w * wv.w;
            }
            pq += __shfl_xor(pq, 1);
            pq += __shfl_xor(pq, 2);
            if (c == 0) s_sc[g][e] = pq + s_bs2[0];
        }
        __syncthreads();

        // ---- masked softmax ----
        if (t < 128) {
            int g = t >> 6, tt = t & 63;
            float v = -INFINITY;
            if (tt < 31)
                v = s_sc[g][tt] * s_emask[g][tt] + (1.0f - s_emask[g][tt]) * (-1e9f);
            float m = v;
#pragma unroll
            for (int d = 32; d >= 1; d >>= 1) m = fmaxf(m, __shfl_xor(m, d));
            float e_ = (tt < 31) ? expf(v - m) : 0.0f;
            float ssum = e_;
#pragma unroll
            for (int d = 32; d >= 1; d >>= 1) ssum += __shfl_xor(ssum, d);
            if (tt < 32) s_w[g][tt] = (tt < 31) ? (e_ / ssum) : 0.0f;
        }
        __syncthreads();

        // ---- P4: weighted pooling ----
        {
            int g = t >> 7, j = t & 127;
            float pp = 0.0f;
#pragma unroll
            for (int e = 0; e < 31; ++e)
                pp += s_he[g * 32 + e][j] * s_w[g][e];
            s_aggf[g][j] = pp;
        }
        __syncthreads();

        // ---- P5: h_glob (Wg read once per pair) ----
        {
            int j = t & 127, half = t >> 7;
            float a0 = 0.0f, a1 = 0.0f;
            for (int k = half * 64; k < half * 64 + 64; ++k) {
                float wv = Wg[k * HG_ + j];
                a0 += s_aggf[0][k] * wv;
                a1 += s_aggf[1][k] * wv;
            }
            s_tmp[half * 256 + j] = a0;
            s_tmp[half * 256 + 128 + j] = a1;
        }
        __syncthreads();
        {
            int g = t >> 7, j = t & 127;
            s_hg[g][j] = fmaxf(s_tmp[g * 128 + j] + s_tmp[256 + g * 128 + j] + s_bg[j], 0.0f);
        }
        __syncthreads();

        // ---- P6: h_cls (Wc1 read once per pair) ----
        {
            int j = t & 63, q = t >> 6;
            float a0 = 0.0f, a1 = 0.0f;
            for (int k = q * 32; k < q * 32 + 32; ++k) {
                float wv = Wc1[k * HC_ + j];
                a0 += s_hg[0][k] * wv;
                a1 += s_hg[1][k] * wv;
            }
            s_tmp[q * 128 + j] = a0;
            s_tmp[q * 128 + 64 + j] = a1;
        }
        __syncthreads();
        if (t < 128) {
            int g = t >> 6, j = t & 63;
            float v = s_bc1[j];
#pragma unroll
            for (int q = 0; q < 4; ++q) v += s_tmp[q * 128 + g * 64 + j];
            s_hc[g][j] = fmaxf(v, 0.0f);
        }
        __syncthreads();

        // ---- P7: output ----
        if (t < 128) {
            int g = t >> 6, tt = t & 63;
            float pp = s_hc[g][tt] * s_Wc2[tt];
#pragma unroll
            for (int d = 32; d >= 1; d >>= 1) pp += __shfl_xor(pp, d);
            if (tt == 0 && 2 * p + g < Btot) out[2 * p + g] = pp + s_bs2[1];
        }
        __syncthreads();   // protect union region before next Phase A
    }
}

// ======================= fallback: f32 kernel =======================
__device__ __forceinline__ void tile_fma_4x4(
    float acc[4][4], const float* in0, const float* in1, const float* in2,
    const float* in3, int k, const float* __restrict__ W, int wrow, int c4)
{
    float in_[4][4];
    *(float4*)&in_[0][0] = *(const float4*)(in0 + k);
    *(float4*)&in_[1][0] = *(const float4*)(in1 + k);
    *(float4*)&in_[2][0] = *(const float4*)(in2 + k);
    *(float4*)&in_[3][0] = *(const float4*)(in3 + k);
#pragma unroll
    for (int kk = 0; kk < 4; ++kk) {
        float w_[4];
        *(float4*)w_ = *(const float4*)&W[(wrow + kk) * 128 + c4];
#pragma unroll
        for (int r = 0; r < 4; ++r)
#pragma unroll
            for (int c = 0; c < 4; ++c)
                acc[r][c] += in_[r][kk] * w_[c];
    }
}

__global__ __launch_bounds__(256, 3) void gnn_fused(
    const float* __restrict__ gf, const float* __restrict__ nf,
    const float* __restrict__ ef, const void* __restrict__ nmask_raw,
    const float* __restrict__ Wn, const float* __restrict__ bn,
    const float* __restrict__ We, const float* __restrict__ be,
    const float* __restrict__ Ws, const float* __restrict__ bs,
    const float* __restrict__ Wg, const float* __restrict__ bg,
    const float* __restrict__ Wc1, const float* __restrict__ bc1,
    const float* __restrict__ Wc2, const float* __restrict__ bc2,
    float* __restrict__ out)
{
    const int b = blockIdx.x;
    const int t = threadIdx.x;

    __shared__ __align__(16) float s_g[GD_];
    __shared__ int   s_mi[N_];
    __shared__ float s_emask[N_];
    __shared__ __align__(16) float s_ef[N_][ED_];
    __shared__ __align__(16) float s_efm[N_][ED_];
    __shared__ __align__(16) float s_nin[N_][32];
    __shared__ __align__(16) float s_hn[N_ + 1][HN_];
    __shared__ __align__(16) float s_he[N_][HE_];
    __shared__ __align__(16) float s_bias1[HN_];
    __shared__ __align__(16) float s_bias2[HE_];
    __shared__ float s_sc[N_];
    __shared__ float s_w[N_];
    __shared__ __align__(16) float s_tmp[256];
    __shared__ __align__(16) float s_aggf[HE_];
    __shared__ __align__(16) float s_hg[HG_];
    __shared__ __align__(16) float s_hc[HC_];

    const unsigned char* mb = (const unsigned char*)nmask_raw;
    int cnt = __syncthreads_count(mb[t] != 0);
    const bool is_u8 = (cnt > 96);

    if (t < GD_) s_g[t] = gf[b * GD_ + t];
    for (int idx = t; idx < N_ * ND_; idx += 256)
        s_nin[idx >> 4][idx & 15] = nf[b * N_ * ND_ + idx];
    for (int idx = t; idx < (N_ - 1) * ED_; idx += 256)
        s_ef[idx >> 3][idx & 7] = ef[b * (N_ - 1) * ED_ + idx];
    if (t < ED_) s_ef[N_ - 1][t] = 0.0f;
    if (t < HN_) s_hn[N_][t] = 0.0f;
    if (t < N_) {
        int mv = is_u8 ? (int)mb[b * N_ + t] : ((const int*)nmask_raw)[b * N_ + t];
        s_mi[t] = mv;
    }
    __syncthreads();

    if (t < N_)
        s_emask[t] = (t < N_ - 1 && s_mi[t] != 0 && s_mi[t + 1] != 0) ? 1.0f : 0.0f;
    __syncthreads();

    {
        int e = t >> 3, k = t & 7;
        s_efm[e][k] = s_ef[e][k] * s_emask[e];
    }
    {
        int j = t & 127;
        if (t < 128) {
            float v = bn[j];
#pragma unroll
            for (int k = 0; k < GD_; ++k)
                v += s_g[k] * Wn[(ND_ + 2 * ED_ + k) * HN_ + j];
            s_bias1[j] = v;
        } else {
            float v = be[j];
#pragma unroll
            for (int k = 0; k < GD_; ++k)
                v += s_g[k] * We[(ED_ + 2 * HN_ + k) * HE_ + j];
            s_bias2[j] = v;
        }
    }
    __syncthreads();

    for (int idx = t; idx < N_ * 16; idx += 256) {
        int n = idx >> 4, kk = idx & 15;
        if (kk < 8) s_nin[n][16 + kk]       = (n > 0)      ? s_efm[n - 1][kk] : 0.0f;
        else        s_nin[n][24 + (kk - 8)] = (n < N_ - 1) ? s_efm[n][kk - 8] : 0.0f;
    }
    __syncthreads();

    const int jg = t & 31, rg = t >> 5;
    const int c4 = jg * 4, r4 = rg * 4;

    {
        float acc[4][4];
#pragma unroll
        for (int r = 0; r < 4; ++r)
#pragma unroll
            for (int c = 0; c < 4; ++c) acc[r][c] = s_bias1[c4 + c];
        const float* i0 = &s_nin[r4 + 0][0];
        const float* i1 = &s_nin[r4 + 1][0];
        const float* i2 = &s_nin[r4 + 2][0];
        const float* i3 = &s_nin[r4 + 3][0];
#pragma unroll
        for (int k = 0; k < 32; k += 4)
            tile_fma_4x4(acc, i0, i1, i2, i3, k, Wn, k, c4);
#pragma unroll
        for (int r = 0; r < 4; ++r)
#pragma unroll
            for (int c = 0; c < 4; ++c)
                s_hn[r4 + r][c4 + c] = fmaxf(acc[r][c], 0.0f);
    }
    __syncthreads();

    {
        float acc[4][4];
#pragma unroll
        for (int r = 0; r < 4; ++r)
#pragma unroll
            for (int c = 0; c < 4; ++c) acc[r][c] = s_bias2[c4 + c];
        {
            const float* i0 = &s_ef[r4 + 0][0];
            const float* i1 = &s_ef[r4 + 1][0];
            const float* i2 = &s_ef[r4 + 2][0];
            const float* i3 = &s_ef[r4 + 3][0];
#pragma unroll
            for (int k = 0; k < 8; k += 4)
                tile_fma_4x4(acc, i0, i1, i2, i3, k, We, k, c4);
        }
        {
            const float* i0 = &s_hn[r4 + 0][0];
            const float* i1 = &s_hn[r4 + 1][0];
            const float* i2 = &s_hn[r4 + 2][0];
            const float* i3 = &s_hn[r4 + 3][0];
#pragma unroll 4
            for (int k = 0; k < 128; k += 4)
                tile_fma_4x4(acc, i0, i1, i2, i3, k, We, 8 + k, c4);
        }
        {
            const float* i0 = &s_hn[r4 + 1][0];
            const float* i1 = &s_hn[r4 + 2][0];
            const float* i2 = &s_hn[r4 + 3][0];
            const float* i3 = &s_hn[r4 + 4][0];
#pragma unroll 4
            for (int k = 0; k < 128; k += 4)
                tile_fma_4x4(acc, i0, i1, i2, i3, k, We, 136 + k, c4);
        }
#pragma unroll
        for (int r = 0; r < 4; ++r)
#pragma unroll
            for (int c = 0; c < 4; ++c)
                s_he[r4 + r][c4 + c] = fmaxf(acc[r][c], 0.0f);
    }
    __syncthreads();

    {
        int c = t & 7, e = t >> 3;
        const float* he = &s_he[e][0];
        float p = 0.0f;
#pragma unroll
        for (int j0 = 0; j0 < 16; j0 += 4) {
            float4 h = *(const float4*)&he[c * 16 + j0];
            float4 wv = *(const float4*)&Ws[c * 16 + j0];
            p += h.x * wv.x + h.y * wv.y + h.z * wv.z + h.w * wv.w;
        }
        p += __shfl_xor(p, 1);
        p += __shfl_xor(p, 2);
        p += __shfl_xor(p, 4);
        if (c == 0) s_sc[e] = p + bs[0];
    }
    __syncthreads();
    if (t < 64) {
        float v = -INFINITY;
        if (t < N_ - 1)
            v = s_sc[t] * s_emask[t] + (1.0f - s_emask[t]) * (-1e9f);
        float m = v;
#pragma unroll
        for (int d = 32; d >= 1; d >>= 1) m = fmaxf(m, __shfl_xor(m, d));
        float e_ = (t < N_ - 1) ? expf(v - m) : 0.0f;
        float ssum = e_;
#pragma unroll
        for (int d = 32; d >= 1; d >>= 1) ssum += __shfl_xor(ssum, d);
        if (t < N_) s_w[t] = (t < N_ - 1) ? (e_ / ssum) : 0.0f;
    }
    __syncthreads();

    {
        int j = t & 127, half = t >> 7;
        float p = 0.0f;
#pragma unroll
        for (int e = 0; e < 16; ++e) {
            int ee = half * 16 + e;
            p += s_he[ee][j] * s_w[ee];
        }
        s_tmp[half * 128 + j] = p;
    }
    __syncthreads();
    if (t < 128) s_aggf[t] = s_tmp[t] + s_tmp[128 + t];
    __syncthreads();

    {
        int j = t & 127, half = t >> 7;
        float p = 0.0f;
        for (int k = half * 64; k < half * 64 + 64; ++k)
            p += s_aggf[k] * Wg[k * HG_ + j];
        s_tmp[half * 128 + j] = p;
    }
    __syncthreads();
    if (t < 128) s_hg[t] = fmaxf(s_tmp[t] + s_tmp[128 + t] + bg[t], 0.0f);
    __syncthreads();

    {
        int j = t & 63, q = t >> 6;
        float p = 0.0f;
        for (int k = q * 32; k < q * 32 + 32; ++k)
            p += s_hg[k] * Wc1[k * HC_ + j];
        s_tmp[q * 64 + j] = p;
    }
    __syncthreads();
    if (t < 64)
        s_hc[t] = fmaxf(s_tmp[t] + s_tmp[64 + t] + s_tmp[128 + t] + s_tmp[192 + t] + bc1[t], 0.0f);
    __syncthreads();

    if (t < 64) {
        float p = s_hc[t] * Wc2[t];
#pragma unroll
        for (int d = 32; d >= 1; d >>= 1) p += __shfl_xor(p, d);
        if (t == 0) out[b] = p + bc2[0];
    }
}

extern "C" void kernel_launch(void* const* d_in, const int* in_sizes, int n_in,
                              void* d_out, int out_size, void* d_ws, size_t ws_size,
                              hipStream_t stream) {
    const float* gf  = (const float*)d_in[0];
    const float* nf  = (const float*)d_in[1];
    const float* ef  = (const float*)d_in[2];
    const void*  nm  = d_in[3];
    const float* Wn  = (const float*)d_in[4];
    const float* bn  = (const float*)d_in[5];
    const float* We  = (const float*)d_in[6];
    const float* be  = (const float*)d_in[7];
    const float* Ws  = (const float*)d_in[8];
    const float* bs  = (const float*)d_in[9];
    const float* Wg  = (const float*)d_in[10];
    const float* bg  = (const float*)d_in[11];
    const float* Wc1 = (const float*)d_in[12];
    const float* bc1 = (const float*)d_in[13];
    const float* Wc2 = (const float*)d_in[14];
    const float* bc2 = (const float*)d_in[15];
    float* out = (float*)d_out;

    const int B = in_sizes[0] / GD_;

    if (ws_size >= (size_t)WS_BYTES && B >= 2) {
        prep_weights<<<20, 256, 0, stream>>>(Wn, We, (unsigned short*)d_ws);
        const int npairs = (B + 1) / 2;
        const int NB = (npairs < 512) ? npairs : 512;
        gnn_persist<<<NB, 256, 0, stream>>>(gf, nf, ef, nm, Wn, bn, We, be, Ws, bs,
                                            Wg, bg, Wc1, bc1, Wc2, bc2,
                                            (const unsigned short*)d_ws, out, B, npairs);
    } else {
        gnn_fused<<<B, 256, 0, stream>>>(gf, nf, ef, nm, Wn, bn, We, be, Ws, bs,
                                         Wg, bg, Wc1, bc1, Wc2, bc2, out);
    }
}

// Round 7
// 119.951 us; speedup vs baseline: 3.7154x; 3.7154x over previous
//
#include <hip/hip_runtime.h>
#include <hip/hip_bf16.h>

#define N_  32
#define ND_ 16
#define ED_ 8
#define GD_ 8
#define HN_ 128
#define HE_ 128
#define HG_ 128
#define HC_ 64

typedef __attribute__((ext_vector_type(8))) short short8_t;
typedef __attribute__((ext_vector_type(4))) float f32x4;

#define MFMA16(a, b, c) __builtin_amdgcn_mfma_f32_16x16x32_bf16((a), (b), (c), 0, 0, 0)

__device__ __forceinline__ unsigned short f2bf(float f) {
    unsigned int u = __float_as_uint(f);
    unsigned int r = u + 0x7FFFu + ((u >> 16) & 1u);
    return (unsigned short)(r >> 16);
}
__device__ __forceinline__ float bf2f(unsigned short h) {
    return __uint_as_float(((unsigned int)h) << 16);
}

// ---- workspace layout (ushort elements) ----
#define WNS_HI 0
#define WNS_LO 4096
#define WES_HI 8192
#define WES_LO (8192 + 36864)
#define WS_USHORTS (8192 + 2 * 36864)
#define WS_BYTES (WS_USHORTS * 2)

// Prologue: convert + swizzle weights into B-fragment-major bf16 hi/lo.
// lane l holds B[k = 32*s + 8*(l>>4)+i][col = 16*n + (l&15)]
__global__ void prep_weights(const float* __restrict__ Wn,
                             const float* __restrict__ We,
                             unsigned short* __restrict__ wsp) {
    int gid = blockIdx.x * 256 + threadIdx.x;
    if (gid >= 512 + 4608) return;
    float vals[8];
    unsigned short* dh;
    unsigned short* dl;
    if (gid < 512) {
        int l = gid & 63, n = (gid >> 6) & 7;
        int c = 16 * n + (l & 15);
#pragma unroll
        for (int i = 0; i < 8; ++i) {
            int k = 8 * (l >> 4) + i;
            vals[i] = Wn[k * HN_ + c];
        }
        dh = wsp + WNS_HI + gid * 8;
        dl = wsp + WNS_LO + gid * 8;
    } else {
        int g2 = gid - 512;
        int l = g2 & 63, n = (g2 >> 6) & 7, s = g2 >> 9;   // s in 0..8
        int c = 16 * n + (l & 15);
#pragma unroll
        for (int i = 0; i < 8; ++i) {
            int kl = 8 * (l >> 4) + i;
            int ks;
            if (s == 0)      ks = (kl < 8) ? kl : -1;          // ef rows 0..7
            else if (s <= 4) ks = 8 + (s - 1) * 32 + kl;       // W1: h_node[e]
            else             ks = 136 + (s - 5) * 32 + kl;     // W2: h_node[e+1]
            vals[i] = (ks >= 0) ? We[ks * HE_ + c] : 0.0f;
        }
        dh = wsp + WES_HI + g2 * 8;
        dl = wsp + WES_LO + g2 * 8;
    }
    unsigned short h[8], lo[8];
#pragma unroll
    for (int i = 0; i < 8; ++i) {
        h[i] = f2bf(vals[i]);
        lo[i] = f2bf(vals[i] - bf2f(h[i]));
    }
    *(short8_t*)dh = *(short8_t*)h;
    *(short8_t*)dl = *(short8_t*)lo;
}

#define HNS 136   // 272 B rows: 16B-aligned, 2-way banks (free)
#define NIS 40    // 80 B rows
#define HES 132   // f32 rows 528 B

// Load edge B-fragment set s (s=0..3 pairs W1-step s+1 with W2-step s+5)
// into buffer d. Indices constant after full unroll -> stays in registers.
#define LOAD_ESET(d, s) do {                                                        \
    Bb[d][0] = *(const short8_t*)(wsp + WES_HI + (((s)+1)*8 + 2*w)     * 512 + l*8); \
    Bb[d][1] = *(const short8_t*)(wsp + WES_HI + (((s)+1)*8 + 2*w + 1) * 512 + l*8); \
    Bb[d][2] = *(const short8_t*)(wsp + WES_LO + (((s)+1)*8 + 2*w)     * 512 + l*8); \
    Bb[d][3] = *(const short8_t*)(wsp + WES_LO + (((s)+1)*8 + 2*w + 1) * 512 + l*8); \
    Bb[d][4] = *(const short8_t*)(wsp + WES_HI + (((s)+5)*8 + 2*w)     * 512 + l*8); \
    Bb[d][5] = *(const short8_t*)(wsp + WES_HI + (((s)+5)*8 + 2*w + 1) * 512 + l*8); \
    Bb[d][6] = *(const short8_t*)(wsp + WES_LO + (((s)+5)*8 + 2*w)     * 512 + l*8); \
    Bb[d][7] = *(const short8_t*)(wsp + WES_LO + (((s)+5)*8 + 2*w + 1) * 512 + l*8); \
} while (0)

// 2 graphs per block, non-persistent. 4 waves x (4 M-tiles x 2 N-tiles).
// Edge MLP software-pipelines its B-fragment L2 loads (double buffer).
__global__ __launch_bounds__(256, 2) void gnn_mfma3(
    const float* __restrict__ gf, const float* __restrict__ nf,
    const float* __restrict__ ef, const void* __restrict__ nmask_raw,
    const float* __restrict__ Wn, const float* __restrict__ bn,
    const float* __restrict__ We, const float* __restrict__ be,
    const float* __restrict__ Ws, const float* __restrict__ bs,
    const float* __restrict__ Wg, const float* __restrict__ bg,
    const float* __restrict__ Wc1, const float* __restrict__ bc1,
    const float* __restrict__ Wc2, const float* __restrict__ bc2,
    const unsigned short* __restrict__ wsp,
    float* __restrict__ out, int Btot)
{
    const int b = blockIdx.x;
    const int t = threadIdx.x;
    const int gid0 = 2 * b;
    const int gid1 = (2 * b + 1 < Btot) ? (2 * b + 1) : (Btot - 1);

    __shared__ __align__(16) unsigned short s_hn_h[2][N_ + 1][HNS];
    __shared__ __align__(16) unsigned short s_hn_l[2][N_ + 1][HNS];
    __shared__ __align__(16) unsigned char u_mem[33792];   // union {nin,efp} / s_he
    __shared__ __align__(16) float s_efraw[2][N_][ED_];
    __shared__ float s_g[2][GD_];
    __shared__ int   s_mi[2][N_];
    __shared__ float s_emask[2][N_];
    __shared__ __align__(16) float s_bias1[2][HN_];
    __shared__ __align__(16) float s_bias2[2][HE_];
    __shared__ float s_sc[2][N_];
    __shared__ float s_w[2][N_];
    __shared__ __align__(16) float s_tmp[512];
    __shared__ __align__(16) float s_aggf[2][HE_];
    __shared__ __align__(16) float s_hg[2][HG_];
    __shared__ __align__(16) float s_hc[2][HC_];

    typedef unsigned short ninrow_t[NIS];
    ninrow_t* s_nin_h = (ninrow_t*)(u_mem);            // [64][40]
    ninrow_t* s_nin_l = (ninrow_t*)(u_mem + 5120);
    ninrow_t* s_efp_h = (ninrow_t*)(u_mem + 10240);
    ninrow_t* s_efp_l = (ninrow_t*)(u_mem + 15360);
    typedef float herow_t[HES];
    herow_t* s_he = (herow_t*)u_mem;                   // [64][132]

    // ---- node_mask dtype detection (u8 vs i32), deterministic ----
    const unsigned char* mb = (const unsigned char*)nmask_raw;
    int cnt = __syncthreads_count(mb[t] != 0);
    const bool is_u8 = (cnt > 96);

    // ---- Phase A: loads + zero fills ----
    if (t < 16) s_g[t >> 3][t & 7] = gf[(t >> 3 ? gid1 : gid0) * GD_ + (t & 7)];
    for (int idx = t; idx < 1024; idx += 256) {        // node feats: 2x32x16
        int g = idx >> 9, rem = idx & 511;
        float v = nf[(g ? gid1 : gid0) * 512 + rem];
        unsigned short h = f2bf(v);
        int r = g * 32 + (rem >> 4), k = rem & 15;
        s_nin_h[r][k] = h;
        s_nin_l[r][k] = f2bf(v - bf2f(h));
    }
    for (int idx = t; idx < 512; idx += 256) {         // raw edges (row31 = 0)
        int g = idx >> 8, rem = idx & 255, e = rem >> 3, k = rem & 7;
        s_efraw[g][e][k] = (e < 31) ? ef[(g ? gid1 : gid0) * 248 + e * 8 + k] : 0.0f;
    }
    for (int idx = t; idx < 2048; idx += 256) {        // efp cols 8..39 zero
        int r = idx >> 5, c = 8 + (idx & 31);
        s_efp_h[r][c] = 0; s_efp_l[r][c] = 0;
    }
    if (t < 16) {                                       // node0 edge_backward zero
        int g = t >> 3, k = t & 7;
        s_nin_h[g * 32][16 + k] = 0; s_nin_l[g * 32][16 + k] = 0;
    }
    for (int idx = t; idx < 2 * HNS; idx += 256) {      // h_node[32] = 0
        int g = (idx >= HNS), c = idx - g * HNS;
        s_hn_h[g][N_][c] = 0; s_hn_l[g][N_][c] = 0;
    }
    if (t < 64) {
        int g = t >> 5, n = t & 31;
        int mv = is_u8 ? (int)mb[(g ? gid1 : gid0) * N_ + n]
                       : ((const int*)nmask_raw)[(g ? gid1 : gid0) * N_ + n];
        s_mi[g][n] = mv;
    }
    __syncthreads();

    // ---- Phase B: edge mask + combined biases ----
    if (t < 64) {
        int g = t >> 5, n = t & 31;
        s_emask[g][n] = (n < 31 && s_mi[g][n] != 0 && s_mi[g][n + 1] != 0) ? 1.0f : 0.0f;
    }
    {
        int g = t >> 7, j = t & 127;
        float v1 = bn[j], v2 = be[j];
#pragma unroll
        for (int k = 0; k < GD_; ++k) {
            v1 += s_g[g][k] * Wn[(ND_ + 2 * ED_ + k) * HN_ + j];
            v2 += s_g[g][k] * We[(ED_ + 2 * HN_ + k) * HE_ + j];
        }
        s_bias1[g][j] = v1;
        s_bias2[g][j] = v2;
    }
    __syncthreads();

    // ---- Phase C: efp fill + nin tail ----
    for (int idx = t; idx < 512; idx += 256) {
        int g = idx >> 8, rem = idx & 255, e = rem >> 3, k = rem & 7;
        int r = g * 32 + e;
        float v = s_efraw[g][e][k];
        unsigned short h = f2bf(v);
        s_efp_h[r][k] = h;
        s_efp_l[r][k] = f2bf(v - bf2f(h));
        float vm = v * s_emask[g][e];
        unsigned short hm = f2bf(vm);
        unsigned short lm = f2bf(vm - bf2f(hm));
        if (e < 31) { s_nin_h[r + 1][16 + k] = hm; s_nin_l[r + 1][16 + k] = lm; }
        s_nin_h[r][24 + k] = hm;
        s_nin_l[r][24 + k] = lm;
    }
    __syncthreads();

    const int w = t >> 6, l = t & 63;
    const int lrow = l & 15;
    const int lk8 = (l >> 4) * 8;
    const int g4 = (l >> 4) * 4;
    const int c0 = 32 * w + lrow, c1 = c0 + 16;

    // ---- Node MLP (MFMA, K=32) ----
    {
        const unsigned short* pn = wsp + (2 * w) * 512 + l * 8;
        short8_t nBh0 = *(const short8_t*)(pn + WNS_HI);
        short8_t nBl0 = *(const short8_t*)(pn + WNS_LO);
        short8_t nBh1 = *(const short8_t*)(pn + WNS_HI + 512);
        short8_t nBl1 = *(const short8_t*)(pn + WNS_LO + 512);

        f32x4 acc[4][2];
#pragma unroll
        for (int mt = 0; mt < 4; ++mt) {
            int g = mt >> 1;
            float b0 = s_bias1[g][c0], b1 = s_bias1[g][c1];
            acc[mt][0] = (f32x4){b0, b0, b0, b0};
            acc[mt][1] = (f32x4){b1, b1, b1, b1};
        }
#pragma unroll
        for (int mt = 0; mt < 4; ++mt) {
            int r = mt * 16 + lrow;
            short8_t Ah = *(const short8_t*)&s_nin_h[r][lk8];
            short8_t Al = *(const short8_t*)&s_nin_l[r][lk8];
            acc[mt][0] = MFMA16(Al, nBh0, acc[mt][0]);
            acc[mt][0] = MFMA16(Ah, nBl0, acc[mt][0]);
            acc[mt][0] = MFMA16(Ah, nBh0, acc[mt][0]);
            acc[mt][1] = MFMA16(Al, nBh1, acc[mt][1]);
            acc[mt][1] = MFMA16(Ah, nBl1, acc[mt][1]);
            acc[mt][1] = MFMA16(Ah, nBh1, acc[mt][1]);
        }
#pragma unroll
        for (int mt = 0; mt < 4; ++mt) {
            int g = mt >> 1, rb = (mt & 1) * 16 + g4;
#pragma unroll
            for (int nt = 0; nt < 2; ++nt) {
                int col = nt ? c1 : c0;
#pragma unroll
                for (int r = 0; r < 4; ++r) {
                    float v = fmaxf(acc[mt][nt][r], 0.0f);
                    unsigned short h = f2bf(v);
                    s_hn_h[g][rb + r][col] = h;
                    s_hn_l[g][rb + r][col] = f2bf(v - bf2f(h));
                }
            }
        }
    }
    __syncthreads();

    // ---- Edge MLP: acc = bias2 + ef@W0 + hn[e]@W1 + hn[e+1]@W2 ----
    // B-fragment loads software-pipelined (double buffer Bb[2][8]).
    float hev[4][2][4];
    {
        // step0 B-fragments
        const unsigned short* pe0 = wsp + WES_HI + (2 * w) * 512 + l * 8;
        short8_t E0h0 = *(const short8_t*)(pe0);
        short8_t E0h1 = *(const short8_t*)(pe0 + 512);
        short8_t E0l0 = *(const short8_t*)(pe0 + 36864);
        short8_t E0l1 = *(const short8_t*)(pe0 + 36864 + 512);

        short8_t Bb[2][8];
        LOAD_ESET(0, 0);                       // prefetch set 0 while step0 runs

        f32x4 acc[4][2];
#pragma unroll
        for (int mt = 0; mt < 4; ++mt) {
            int g = mt >> 1;
            float b0 = s_bias2[g][c0], b1 = s_bias2[g][c1];
            acc[mt][0] = (f32x4){b0, b0, b0, b0};
            acc[mt][1] = (f32x4){b1, b1, b1, b1};
        }
        // step0: raw edge features
#pragma unroll
        for (int mt = 0; mt < 4; ++mt) {
            int r = mt * 16 + lrow;
            short8_t Ah = *(const short8_t*)&s_efp_h[r][lk8];
            short8_t Al = *(const short8_t*)&s_efp_l[r][lk8];
            acc[mt][0] = MFMA16(Al, E0h0, acc[mt][0]);
            acc[mt][0] = MFMA16(Ah, E0l0, acc[mt][0]);
            acc[mt][0] = MFMA16(Ah, E0h0, acc[mt][0]);
            acc[mt][1] = MFMA16(Al, E0h1, acc[mt][1]);
            acc[mt][1] = MFMA16(Ah, E0l1, acc[mt][1]);
            acc[mt][1] = MFMA16(Ah, E0h1, acc[mt][1]);
        }
        // steps s=0..3: A1 = hn[e] @ W1-step, A2 = hn[e+1] @ W2-step
#pragma unroll
        for (int s = 0; s < 4; ++s) {
            if (s < 3) {
                if ((s & 1) == 0) { LOAD_ESET(1, s + 1); }
                else              { LOAD_ESET(0, s + 1); }
            }
            const int d = s & 1;
            int kb = s * 32 + lk8;
#pragma unroll
            for (int mt = 0; mt < 4; ++mt) {
                int g = mt >> 1, lr = (mt & 1) * 16 + lrow;
                short8_t A1h = *(const short8_t*)&s_hn_h[g][lr][kb];
                short8_t A1l = *(const short8_t*)&s_hn_l[g][lr][kb];
                short8_t A2h = *(const short8_t*)&s_hn_h[g][lr + 1][kb];
                short8_t A2l = *(const short8_t*)&s_hn_l[g][lr + 1][kb];
                acc[mt][0] = MFMA16(A1l, Bb[d][0], acc[mt][0]);
                acc[mt][0] = MFMA16(A1h, Bb[d][2], acc[mt][0]);
                acc[mt][0] = MFMA16(A1h, Bb[d][0], acc[mt][0]);
                acc[mt][1] = MFMA16(A1l, Bb[d][1], acc[mt][1]);
                acc[mt][1] = MFMA16(A1h, Bb[d][3], acc[mt][1]);
                acc[mt][1] = MFMA16(A1h, Bb[d][1], acc[mt][1]);
                acc[mt][0] = MFMA16(A2l, Bb[d][4], acc[mt][0]);
                acc[mt][0] = MFMA16(A2h, Bb[d][6], acc[mt][0]);
                acc[mt][0] = MFMA16(A2h, Bb[d][4], acc[mt][0]);
                acc[mt][1] = MFMA16(A2l, Bb[d][5], acc[mt][1]);
                acc[mt][1] = MFMA16(A2h, Bb[d][7], acc[mt][1]);
                acc[mt][1] = MFMA16(A2h, Bb[d][5], acc[mt][1]);
            }
        }
#pragma unroll
        for (int mt = 0; mt < 4; ++mt)
#pragma unroll
            for (int nt = 0; nt < 2; ++nt)
#pragma unroll
                for (int r = 0; r < 4; ++r)
                    hev[mt][nt][r] = fmaxf(acc[mt][nt][r], 0.0f);
    }
    __syncthreads();   // all efp/nin reads done -> safe to overlay s_he
#pragma unroll
    for (int mt = 0; mt < 4; ++mt) {
        int rb = mt * 16 + g4;
#pragma unroll
        for (int nt = 0; nt < 2; ++nt) {
            int col = nt ? c1 : c0;
#pragma unroll
            for (int r = 0; r < 4; ++r)
                s_he[rb + r][col] = hev[mt][nt][r];
        }
    }
    __syncthreads();

    // ---- P3: scores (64 edges x 4 lanes) ----
    {
        int c = t & 3, eg = t >> 2;
        int g = eg >> 5, e = eg & 31;
        const float* he = &s_he[g * 32 + e][0];
        float pq = 0.0f;
#pragma unroll
        for (int j0 = 0; j0 < 32; j0 += 4) {
            float4 h = *(const float4*)&he[c * 32 + j0];
            float4 wv = *(const float4*)&Ws[c * 32 + j0];
            pq += h.x * wv.x + h.y * wv.y + h.z * wv.z + h.w * wv.w;
        }
        pq += __shfl_xor(pq, 1);
        pq += __shfl_xor(pq, 2);
        if (c == 0) s_sc[g][e] = pq + bs[0];
    }
    __syncthreads();

    // ---- masked softmax (graph g on wave g) ----
    if (t < 128) {
        int g = t >> 6, tt = t & 63;
        float v = -INFINITY;
        if (tt < 31)
            v = s_sc[g][tt] * s_emask[g][tt] + (1.0f - s_emask[g][tt]) * (-1e9f);
        float m = v;
#pragma unroll
        for (int d = 32; d >= 1; d >>= 1) m = fmaxf(m, __shfl_xor(m, d));
        float e_ = (tt < 31) ? expf(v - m) : 0.0f;
        float ssum = e_;
#pragma unroll
        for (int d = 32; d >= 1; d >>= 1) ssum += __shfl_xor(ssum, d);
        if (tt < 32) s_w[g][tt] = (tt < 31) ? (e_ / ssum) : 0.0f;
    }
    __syncthreads();

    // ---- P4: weighted edge pooling ----
    {
        int g = t >> 7, j = t & 127;
        float pp = 0.0f;
#pragma unroll
        for (int e = 0; e < 31; ++e)
            pp += s_he[g * 32 + e][j] * s_w[g][e];
        s_aggf[g][j] = pp;
    }
    __syncthreads();

    // ---- P5: h_glob (Wg read once per pair) ----
    {
        int j = t & 127, half = t >> 7;
        float a0 = 0.0f, a1 = 0.0f;
        for (int k = half * 64; k < half * 64 + 64; ++k) {
            float wv = Wg[k * HG_ + j];
            a0 += s_aggf[0][k] * wv;
            a1 += s_aggf[1][k] * wv;
        }
        s_tmp[half * 256 + j] = a0;
        s_tmp[half * 256 + 128 + j] = a1;
    }
    __syncthreads();
    {
        int g = t >> 7, j = t & 127;
        s_hg[g][j] = fmaxf(s_tmp[g * 128 + j] + s_tmp[256 + g * 128 + j] + bg[j], 0.0f);
    }
    __syncthreads();

    // ---- P6: h_cls (Wc1 read once per pair) ----
    {
        int j = t & 63, q = t >> 6;
        float a0 = 0.0f, a1 = 0.0f;
        for (int k = q * 32; k < q * 32 + 32; ++k) {
            float wv = Wc1[k * HC_ + j];
            a0 += s_hg[0][k] * wv;
            a1 += s_hg[1][k] * wv;
        }
        s_tmp[q * 128 + j] = a0;
        s_tmp[q * 128 + 64 + j] = a1;
    }
    __syncthreads();
    if (t < 128) {
        int g = t >> 6, j = t & 63;
        float v = bc1[j];
#pragma unroll
        for (int q = 0; q < 4; ++q) v += s_tmp[q * 128 + g * 64 + j];
        s_hc[g][j] = fmaxf(v, 0.0f);
    }
    __syncthreads();

    // ---- P7: y = h_cls @ Wc2 + bc2 ----
    if (t < 128) {
        int g = t >> 6, tt = t & 63;
        float pp = s_hc[g][tt] * Wc2[tt];
#pragma unroll
        for (int d = 32; d >= 1; d >>= 1) pp += __shfl_xor(pp, d);
        if (tt == 0 && 2 * b + g < Btot) out[2 * b + g] = pp + bc2[0];
    }
}

// ======================= fallback: f32 kernel =======================
__device__ __forceinline__ void tile_fma_4x4(
    float acc[4][4], const float* in0, const float* in1, const float* in2,
    const float* in3, int k, const float* __restrict__ W, int wrow, int c4)
{
    float in_[4][4];
    *(float4*)&in_[0][0] = *(const float4*)(in0 + k);
    *(float4*)&in_[1][0] = *(const float4*)(in1 + k);
    *(float4*)&in_[2][0] = *(const float4*)(in2 + k);
    *(float4*)&in_[3][0] = *(const float4*)(in3 + k);
#pragma unroll
    for (int kk = 0; kk < 4; ++kk) {
        float w_[4];
        *(float4*)w_ = *(const float4*)&W[(wrow + kk) * 128 + c4];
#pragma unroll
        for (int r = 0; r < 4; ++r)
#pragma unroll
            for (int c = 0; c < 4; ++c)
                acc[r][c] += in_[r][kk] * w_[c];
    }
}

__global__ __launch_bounds__(256, 3) void gnn_fused(
    const float* __restrict__ gf, const float* __restrict__ nf,
    const float* __restrict__ ef, const void* __restrict__ nmask_raw,
    const float* __restrict__ Wn, const float* __restrict__ bn,
    const float* __restrict__ We, const float* __restrict__ be,
    const float* __restrict__ Ws, const float* __restrict__ bs,
    const float* __restrict__ Wg, const float* __restrict__ bg,
    const float* __restrict__ Wc1, const float* __restrict__ bc1,
    const float* __restrict__ Wc2, const float* __restrict__ bc2,
    float* __restrict__ out)
{
    const int b = blockIdx.x;
    const int t = threadIdx.x;

    __shared__ __align__(16) float s_g[GD_];
    __shared__ int   s_mi[N_];
    __shared__ float s_emask[N_];
    __shared__ __align__(16) float s_ef[N_][ED_];
    __shared__ __align__(16) float s_efm[N_][ED_];
    __shared__ __align__(16) float s_nin[N_][32];
    __shared__ __align__(16) float s_hn[N_ + 1][HN_];
    __shared__ __align__(16) float s_he[N_][HE_];
    __shared__ __align__(16) float s_bias1[HN_];
    __shared__ __align__(16) float s_bias2[HE_];
    __shared__ float s_sc[N_];
    __shared__ float s_w[N_];
    __shared__ __align__(16) float s_tmp[256];
    __shared__ __align__(16) float s_aggf[HE_];
    __shared__ __align__(16) float s_hg[HG_];
    __shared__ __align__(16) float s_hc[HC_];

    const unsigned char* mb = (const unsigned char*)nmask_raw;
    int cnt = __syncthreads_count(mb[t] != 0);
    const bool is_u8 = (cnt > 96);

    if (t < GD_) s_g[t] = gf[b * GD_ + t];
    for (int idx = t; idx < N_ * ND_; idx += 256)
        s_nin[idx >> 4][idx & 15] = nf[b * N_ * ND_ + idx];
    for (int idx = t; idx < (N_ - 1) * ED_; idx += 256)
        s_ef[idx >> 3][idx & 7] = ef[b * (N_ - 1) * ED_ + idx];
    if (t < ED_) s_ef[N_ - 1][t] = 0.0f;
    if (t < HN_) s_hn[N_][t] = 0.0f;
    if (t < N_) {
        int mv = is_u8 ? (int)mb[b * N_ + t] : ((const int*)nmask_raw)[b * N_ + t];
        s_mi[t] = mv;
    }
    __syncthreads();

    if (t < N_)
        s_emask[t] = (t < N_ - 1 && s_mi[t] != 0 && s_mi[t + 1] != 0) ? 1.0f : 0.0f;
    __syncthreads();

    {
        int e = t >> 3, k = t & 7;
        s_efm[e][k] = s_ef[e][k] * s_emask[e];
    }
    {
        int j = t & 127;
        if (t < 128) {
            float v = bn[j];
#pragma unroll
            for (int k = 0; k < GD_; ++k)
                v += s_g[k] * Wn[(ND_ + 2 * ED_ + k) * HN_ + j];
            s_bias1[j] = v;
        } else {
            float v = be[j];
#pragma unroll
            for (int k = 0; k < GD_; ++k)
                v += s_g[k] * We[(ED_ + 2 * HN_ + k) * HE_ + j];
            s_bias2[j] = v;
        }
    }
    __syncthreads();

    for (int idx = t; idx < N_ * 16; idx += 256) {
        int n = idx >> 4, kk = idx & 15;
        if (kk < 8) s_nin[n][16 + kk]       = (n > 0)      ? s_efm[n - 1][kk] : 0.0f;
        else        s_nin[n][24 + (kk - 8)] = (n < N_ - 1) ? s_efm[n][kk - 8] : 0.0f;
    }
    __syncthreads();

    const int jg = t & 31, rg = t >> 5;
    const int c4 = jg * 4, r4 = rg * 4;

    {
        float acc[4][4];
#pragma unroll
        for (int r = 0; r < 4; ++r)
#pragma unroll
            for (int c = 0; c < 4; ++c) acc[r][c] = s_bias1[c4 + c];
        const float* i0 = &s_nin[r4 + 0][0];
        const float* i1 = &s_nin[r4 + 1][0];
        const float* i2 = &s_nin[r4 + 2][0];
        const float* i3 = &s_nin[r4 + 3][0];
#pragma unroll
        for (int k = 0; k < 32; k += 4)
            tile_fma_4x4(acc, i0, i1, i2, i3, k, Wn, k, c4);
#pragma unroll
        for (int r = 0; r < 4; ++r)
#pragma unroll
            for (int c = 0; c < 4; ++c)
                s_hn[r4 + r][c4 + c] = fmaxf(acc[r][c], 0.0f);
    }
    __syncthreads();

    {
        float acc[4][4];
#pragma unroll
        for (int r = 0; r < 4; ++r)
#pragma unroll
            for (int c = 0; c < 4; ++c) acc[r][c] = s_bias2[c4 + c];
        {
            const float* i0 = &s_ef[r4 + 0][0];
            const float* i1 = &s_ef[r4 + 1][0];
            const float* i2 = &s_ef[r4 + 2][0];
            const float* i3 = &s_ef[r4 + 3][0];
#pragma unroll
            for (int k = 0; k < 8; k += 4)
                tile_fma_4x4(acc, i0, i1, i2, i3, k, We, k, c4);
        }
        {
            const float* i0 = &s_hn[r4 + 0][0];
            const float* i1 = &s_hn[r4 + 1][0];
            const float* i2 = &s_hn[r4 + 2][0];
            const float* i3 = &s_hn[r4 + 3][0];
#pragma unroll 4
            for (int k = 0; k < 128; k += 4)
                tile_fma_4x4(acc, i0, i1, i2, i3, k, We, 8 + k, c4);
        }
        {
            const float* i0 = &s_hn[r4 + 1][0];
            const float* i1 = &s_hn[r4 + 2][0];
            const float* i2 = &s_hn[r4 + 3][0];
            const float* i3 = &s_hn[r4 + 4][0];
#pragma unroll 4
            for (int k = 0; k < 128; k += 4)
                tile_fma_4x4(acc, i0, i1, i2, i3, k, We, 136 + k, c4);
        }
#pragma unroll
        for (int r = 0; r < 4; ++r)
#pragma unroll
            for (int c = 0; c < 4; ++c)
                s_he[r4 + r][c4 + c] = fmaxf(acc[r][c], 0.0f);
    }
    __syncthreads();

    {
        int c = t & 7, e = t >> 3;
        const float* he = &s_he[e][0];
        float p = 0.0f;
#pragma unroll
        for (int j0 = 0; j0 < 16; j0 += 4) {
            float4 h = *(const float4*)&he[c * 16 + j0];
            float4 wv = *(const float4*)&Ws[c * 16 + j0];
            p += h.x * wv.x + h.y * wv.y + h.z * wv.z + h.w * wv.w;
        }
        p += __shfl_xor(p, 1);
        p += __shfl_xor(p, 2);
        p += __shfl_xor(p, 4);
        if (c == 0) s_sc[e] = p + bs[0];
    }
    __syncthreads();
    if (t < 64) {
        float v = -INFINITY;
        if (t < N_ - 1)
            v = s_sc[t] * s_emask[t] + (1.0f - s_emask[t]) * (-1e9f);
        float m = v;
#pragma unroll
        for (int d = 32; d >= 1; d >>= 1) m = fmaxf(m, __shfl_xor(m, d));
        float e_ = (t < N_ - 1) ? expf(v - m) : 0.0f;
        float ssum = e_;
#pragma unroll
        for (int d = 32; d >= 1; d >>= 1) ssum += __shfl_xor(ssum, d);
        if (t < N_) s_w[t] = (t < N_ - 1) ? (e_ / ssum) : 0.0f;
    }
    __syncthreads();

    {
        int j = t & 127, half = t >> 7;
        float p = 0.0f;
#pragma unroll
        for (int e = 0; e < 16; ++e) {
            int ee = half * 16 + e;
            p += s_he[ee][j] * s_w[ee];
        }
        s_tmp[half * 128 + j] = p;
    }
    __syncthreads();
    if (t < 128) s_aggf[t] = s_tmp[t] + s_tmp[128 + t];
    __syncthreads();

    {
        int j = t & 127, half = t >> 7;
        float p = 0.0f;
        for (int k = half * 64; k < half * 64 + 64; ++k)
            p += s_aggf[k] * Wg[k * HG_ + j];
        s_tmp[half * 128 + j] = p;
    }
    __syncthreads();
    if (t < 128) s_hg[t] = fmaxf(s_tmp[t] + s_tmp[128 + t] + bg[t], 0.0f);
    __syncthreads();

    {
        int j = t & 63, q = t >> 6;
        float p = 0.0f;
        for (int k = q * 32; k < q * 32 + 32; ++k)
            p += s_hg[k] * Wc1[k * HC_ + j];
        s_tmp[q * 64 + j] = p;
    }
    __syncthreads();
    if (t < 64)
        s_hc[t] = fmaxf(s_tmp[t] + s_tmp[64 + t] + s_tmp[128 + t] + s_tmp[192 + t] + bc1[t], 0.0f);
    __syncthreads();

    if (t < 64) {
        float p = s_hc[t] * Wc2[t];
#pragma unroll
        for (int d = 32; d >= 1; d >>= 1) p += __shfl_xor(p, d);
        if (t == 0) out[b] = p + bc2[0];
    }
}

extern "C" void kernel_launch(void* const* d_in, const int* in_sizes, int n_in,
                              void* d_out, int out_size, void* d_ws, size_t ws_size,
                              hipStream_t stream) {
    const float* gf  = (const float*)d_in[0];
    const float* nf  = (const float*)d_in[1];
    const float* ef  = (const float*)d_in[2];
    const void*  nm  = d_in[3];
    const float* Wn  = (const float*)d_in[4];
    const float* bn  = (const float*)d_in[5];
    const float* We  = (const float*)d_in[6];
    const float* be  = (const float*)d_in[7];
    const float* Ws  = (const float*)d_in[8];
    const float* bs  = (const float*)d_in[9];
    const float* Wg  = (const float*)d_in[10];
    const float* bg  = (const float*)d_in[11];
    const float* Wc1 = (const float*)d_in[12];
    const float* bc1 = (const float*)d_in[13];
    const float* Wc2 = (const float*)d_in[14];
    const float* bc2 = (const float*)d_in[15];
    float* out = (float*)d_out;

    const int B = in_sizes[0] / GD_;

    if (ws_size >= (size_t)WS_BYTES && B >= 2) {
        prep_weights<<<20, 256, 0, stream>>>(Wn, We, (unsigned short*)d_ws);
        const int NB = (B + 1) / 2;
        gnn_mfma3<<<NB, 256, 0, stream>>>(gf, nf, ef, nm, Wn, bn, We, be, Ws, bs,
                                          Wg, bg, Wc1, bc1, Wc2, bc2,
                                          (const unsigned short*)d_ws, out, B);
    } else {
        gnn_fused<<<B, 256, 0, stream>>>(gf, nf, ef, nm, Wn, bn, We, be, Ws, bs,
                                         Wg, bg, Wc1, bc1, Wc2, bc2, out);
    }
}